// Round 14
// baseline (54.616 us; speedup 1.0000x reference)
//
#include <hip/hip_runtime.h>

// VectorQuantization: x (32,64,64,64) f32, embedding (512,64) f32
// out = [quantized_ste (8388608 f32)] ++ [loss (1 f32)]
//
// score[k,n] = e2[k] + dot(f16(-2e_k), f16hi(x_n)+f16lo(x_n)); 2-pass f16 MFMA
// (A-side-only error, sigma ~1.3e-3). Per-lh-group top-2 (8 candidates/vec,
// disjoint k-subsets) + fp64 refine of all candidates within W=2.5e-2.
// Round 14: NO LDS A-table -- MFMA A-fragments loaded straight from the
// global frag-linear table (L2-resident, coalesced 16B/lane). LDS = 2.6KB
// (e2 only) -> occupancy capped by VGPR: launch_bounds(256,4) = 16 waves/CU.

#define C_DIM 64
#define K_EMB 512
#define NVEC (32 * 64 * 64)     // 131072
#define BLK 256                 // 4 waves
#define VPW 64                  // vectors per wave
#define NPB 256                 // vectors per block
#define GRID (NVEC / NPB)       // 512
#define KT (K_EMB / 16)         // 32 k-tiles
#define NT 4                    // 16-vector groups per wave
#define WINF 2.5e-2f

typedef __attribute__((ext_vector_type(8))) _Float16 f16x8;
typedef __attribute__((ext_vector_type(4))) float f32x4;

// ws layout (bytes)
#define WS_E2   0
#define WS_AE   4096
#define WS_PART (4096 + 65536)

__device__ inline bool lessidx(float s, int i, float t, int j) {
    return (s < t) || (s == t && i < j);
}

__device__ __forceinline__ double dist64(const float4* __restrict__ xq,
                                         const float* __restrict__ ep) {
    const float4* e4 = (const float4*)ep;
    double s = 0.0;
#pragma unroll
    for (int i = 0; i < 16; ++i) {
        float4 xv = xq[i]; float4 a = e4[i];
        double d;
        d = (double)xv.x - (double)a.x; s = fma(d, d, s);
        d = (double)xv.y - (double)a.y; s = fma(d, d, s);
        d = (double)xv.z - (double)a.z; s = fma(d, d, s);
        d = (double)xv.w - (double)a.w; s = fma(d, d, s);
    }
    return s;
}

// ---- prep: e2[k]; frag-linear f16 table of (-2*emb) ----
// frag layout: region r = kt*2 + s, lane l holds 8 f16 =
// A[row = kt*16 + (l&15)][c = 32*s + (l>>4)*8 + j], at (r*64+l)*8 halfs.
__global__ __launch_bounds__(512) void vq_prep(const float* __restrict__ emb,
                                               float* __restrict__ e2,
                                               short* __restrict__ ae) {
    const int t = blockIdx.x * 512 + threadIdx.x;   // 0..4095
    const int l = t & 63;
    const int kt2 = t >> 6;
    const int row = (kt2 >> 1) * 16 + (l & 15);
    const int cb  = (kt2 & 1) * 32 + (l >> 4) * 8;
    const float* src = emb + row * C_DIM + cb;
    f16x8 vh;
#pragma unroll
    for (int j = 0; j < 8; ++j) vh[j] = (_Float16)(-2.0f * src[j]);
    *(f16x8*)(ae + (size_t)t * 8) = vh;

    if (t < K_EMB) {
        const float* r = emb + t * C_DIM;
        float s = 0.f;
#pragma unroll
        for (int c = 0; c < C_DIM; ++c) s += r[c] * r[c];
        e2[t] = s;
    }
}

__global__ __launch_bounds__(BLK, 4) void vq_main(
    const float* __restrict__ x,
    const float* __restrict__ emb,
    const float* __restrict__ e2g,
    const short* __restrict__ ae_g,
    float* __restrict__ out,
    double* __restrict__ partials)
{
    __shared__ __align__(16) float s_e2[K_EMB];          // 2 KB (only LDS)
    __shared__ double s_wsum[BLK / 64];

    const int tid  = threadIdx.x;
    const int lane = tid & 63;
    const int wid  = tid >> 6;
    const int lr   = lane & 15;
    const int lh   = lane >> 4;
    const int nbase = blockIdx.x * NPB + wid * VPW;

    // ---- x loads (in flight during e2 stage) ----
    float4 xr[NT * 4];
#pragma unroll
    for (int nt = 0; nt < NT; ++nt) {
        const float* xp = x + (size_t)(nbase + nt * 16 + lr) * C_DIM;
#pragma unroll
        for (int s = 0; s < 2; ++s) {
            xr[nt * 4 + s * 2 + 0] = *(const float4*)(xp + s * 32 + lh * 8);
            xr[nt * 4 + s * 2 + 1] = *(const float4*)(xp + s * 32 + lh * 8 + 4);
        }
    }

    // ---- stage e2 (2 KB) ----
    s_e2[tid] = e2g[tid];
    s_e2[tid + 256] = e2g[tid + 256];
    __syncthreads();

    // ---- x -> f16 hi/lo B-fragments, x2 partials ----
    f16x8 xh[NT][2], xl[NT][2];
    float x2p[NT];
#pragma unroll
    for (int nt = 0; nt < NT; ++nt) {
        x2p[nt] = 0.f;
#pragma unroll
        for (int s = 0; s < 2; ++s) {
            float4 a = xr[nt * 4 + s * 2 + 0];
            float4 b = xr[nt * 4 + s * 2 + 1];
            float vv[8] = {a.x, a.y, a.z, a.w, b.x, b.y, b.z, b.w};
#pragma unroll
            for (int j = 0; j < 8; ++j) {
                float v = vv[j];
                x2p[nt] += v * v;
                _Float16 h = (_Float16)v;
                xh[nt][s][j] = h;
                xl[nt][s][j] = (_Float16)(v - (float)h);
            }
        }
    }

    // ---- k-loop: A-frags from GLOBAL (L2-hit, coalesced), 16 MFMA/kt ----
    float pb1[NT] = {1e30f, 1e30f, 1e30f, 1e30f};
    float pb2[NT] = {1e30f, 1e30f, 1e30f, 1e30f};
    const f16x8* ag = (const f16x8*)ae_g + lane;

#pragma unroll 2
    for (int kt = 0; kt < KT; ++kt) {
        f16x8 a0 = ag[kt * 128], a1 = ag[kt * 128 + 64];
        f32x4 ev = *(const f32x4*)(s_e2 + kt * 16 + lh * 4);
        f32x4 c[NT];
#pragma unroll
        for (int nt = 0; nt < NT; ++nt) c[nt] = ev;
#pragma unroll
        for (int nt = 0; nt < NT; ++nt)
            c[nt] = __builtin_amdgcn_mfma_f32_16x16x32_f16(a0, xh[nt][0], c[nt], 0, 0, 0);
#pragma unroll
        for (int nt = 0; nt < NT; ++nt)
            c[nt] = __builtin_amdgcn_mfma_f32_16x16x32_f16(a1, xh[nt][1], c[nt], 0, 0, 0);
#pragma unroll
        for (int nt = 0; nt < NT; ++nt)
            c[nt] = __builtin_amdgcn_mfma_f32_16x16x32_f16(a0, xl[nt][0], c[nt], 0, 0, 0);
#pragma unroll
        for (int nt = 0; nt < NT; ++nt)
            c[nt] = __builtin_amdgcn_mfma_f32_16x16x32_f16(a1, xl[nt][1], c[nt], 0, 0, 0);

        const unsigned kb4 = (unsigned)(kt * 4);
#pragma unroll
        for (int nt = 0; nt < NT; ++nt) {
            unsigned q0 = (__float_as_uint(c[nt][0]) & 0xFFFFFF80u) | (kb4 + 0);
            unsigned q1 = (__float_as_uint(c[nt][1]) & 0xFFFFFF80u) | (kb4 + 1);
            unsigned q2 = (__float_as_uint(c[nt][2]) & 0xFFFFFF80u) | (kb4 + 2);
            unsigned q3 = (__float_as_uint(c[nt][3]) & 0xFFFFFF80u) | (kb4 + 3);
            float f0 = __uint_as_float(q0), f1 = __uint_as_float(q1);
            float f2 = __uint_as_float(q2), f3 = __uint_as_float(q3);
            float lo = fminf(f0, f1), hi = fmaxf(f0, f1);
            pb2[nt] = fminf(fminf(pb2[nt], fmaxf(pb1[nt], lo)), hi);
            pb1[nt] = fminf(pb1[nt], lo);
            lo = fminf(f2, f3); hi = fmaxf(f2, f3);
            pb2[nt] = fminf(fminf(pb2[nt], fmaxf(pb1[nt], lo)), hi);
            pb1[nt] = fminf(pb1[nt], lo);
        }
    }

    // ---- per-nt: unpack, merge, conditional 8-candidate fp64 refine ----
    double dsum = 0.0;
#pragma unroll
    for (int nt = 0; nt < NT; ++nt) {
        unsigned u1 = __float_as_uint(pb1[nt]);
        unsigned u2 = __float_as_uint(pb2[nt]);
        int loc1 = u1 & 127, loc2 = u2 & 127;
        float b1 = __uint_as_float(u1 & 0xFFFFFF80u);
        float b2 = __uint_as_float(u2 & 0xFFFFFF80u);
        int i1 = ((loc1 >> 2) << 4) + lh * 4 + (loc1 & 3);
        int i2 = ((loc2 >> 2) << 4) + lh * 4 + (loc2 & 3);
        const float os1 = b1, os2 = b2;
        const int   oi1 = i1, oi2 = i2;

        float xx = x2p[nt];
#pragma unroll
        for (int off = 16; off <= 32; off <<= 1) {
            float ob1 = __shfl_xor(b1, off, 64);
            int   oI1 = __shfl_xor(i1, off, 64);
            float ob2 = __shfl_xor(b2, off, 64);
            int   oI2 = __shfl_xor(i2, off, 64);
            float oxx = __shfl_xor(xx, off, 64);
            xx += oxx;
            bool to = lessidx(ob1, oI1, b1, i1);
            float w1 = to ? ob1 : b1;  int wi1 = to ? oI1 : i1;
            float l1 = to ? b1 : ob1;  int li1 = to ? i1 : oI1;
            float c2 = to ? ob2 : b2;  int ci2 = to ? oI2 : i2;
            bool t2 = lessidx(l1, li1, c2, ci2);
            b1 = w1; i1 = wi1;
            b2 = t2 ? l1 : c2; i2 = t2 ? li1 : ci2;
        }

        const int n = nbase + nt * 16 + lr;
        const float4* xq = (const float4*)(x + (size_t)n * C_DIM);

        int bw;
        double md;
        // condition uniform across the 4 lanes of a column -> shfl-safe
        if (b2 - b1 < WINF) {
            bool f1 = (os1 <= b1 + WINF);
            bool f2 = (os2 <= b1 + WINF);
            double d1 = 1e300, d2 = 1e300;
            if (f1) d1 = dist64(xq, emb + (size_t)oi1 * C_DIM);
            if (f2) d2 = dist64(xq, emb + (size_t)oi2 * C_DIM);
            bool t = (d2 < d1) || (d2 == d1 && oi2 < oi1);
            double dl = t ? d2 : d1;
            int    il = t ? oi2 : oi1;
#pragma unroll
            for (int off = 16; off <= 32; off <<= 1) {
                double od = __shfl_xor(dl, off, 64);
                int    oi = __shfl_xor(il, off, 64);
                bool tk = (od < dl) || (od == dl && oi < il);
                dl = tk ? od : dl;
                il = tk ? oi : il;
            }
            bw = il;
            md = dl;
        } else {
            bw = i1;
            md = (double)xx + (double)b1;
        }

        if (lane < 16) dsum += md;

        // per-wave gather: 16 vectors x 16 float4 chunks, 4 iters of 64 lanes
        {
            const int v  = lane >> 2;
            const int c0 = lane & 3;
            const int w  = __shfl(bw, v);
            const size_t rowb = ((size_t)(nbase + nt * 16 + v)) * 16;
            const float4* ep = (const float4*)emb + (size_t)w * 16;
            float4* op = (float4*)out;
#pragma unroll
            for (int it = 0; it < 4; ++it) op[rowb + c0 + it * 4] = ep[c0 + it * 4];
        }
    }

    // ---- loss partial ----
#pragma unroll
    for (int off = 1; off <= 8; off <<= 1) dsum += __shfl_xor(dsum, off, 64);
    if (lane == 0) s_wsum[wid] = dsum;
    __syncthreads();
    if (tid == 0) {
        double t = 0.0;
#pragma unroll
        for (int i = 0; i < BLK / 64; ++i) t += s_wsum[i];
        partials[blockIdx.x] = t;
    }
}

__global__ __launch_bounds__(512) void vq_finalize(const double* __restrict__ partials,
                                                   float* __restrict__ out) {
    double v = partials[threadIdx.x];   // 512 partials
#pragma unroll
    for (int off = 32; off; off >>= 1) v += __shfl_down(v, off, 64);
    __shared__ double ls[8];
    const int lane = threadIdx.x & 63;
    const int wid  = threadIdx.x >> 6;
    if (lane == 0) ls[wid] = v;
    __syncthreads();
    if (threadIdx.x == 0) {
        double t = 0.0;
#pragma unroll
        for (int i = 0; i < 8; ++i) t += ls[i];
        double mean = t / (double)((size_t)NVEC * C_DIM);
        out[(size_t)NVEC * C_DIM] = (float)(1.25 * mean);
    }
}

extern "C" void kernel_launch(void* const* d_in, const int* in_sizes, int n_in,
                              void* d_out, int out_size, void* d_ws, size_t ws_size,
                              hipStream_t stream) {
    const float* x   = (const float*)d_in[0];
    const float* emb = (const float*)d_in[1];
    float* out = (float*)d_out;

    float*  e2       = (float*)((char*)d_ws + WS_E2);
    short*  ae       = (short*)((char*)d_ws + WS_AE);
    double* partials = (double*)((char*)d_ws + WS_PART);

    vq_prep<<<8, 512, 0, stream>>>(emb, e2, ae);
    vq_main<<<GRID, BLK, 0, stream>>>(x, emb, e2, ae, out, partials);
    vq_finalize<<<1, 512, 0, stream>>>(partials, out);
}

// Round 15
// 43.853 us; speedup vs baseline: 1.2454x; 1.2454x over previous
//
#include <hip/hip_runtime.h>

// VectorQuantization: x (32,64,64,64) f32, embedding (512,64) f32
// out = [quantized_ste (8388608 f32)] ++ [loss (1 f32)]
//
// FINAL (r11 champion, restored): score[k,n] = e2[k] + dot(f16(-2e_k),
// f16hi(x_n)+f16lo(x_n)); 2-pass f16 MFMA (A-side-only error ~1.3e-3 sigma).
// Per-lh-group top-2 (8 candidates/vec, disjoint 128-k subsets) + fp64
// refine of all candidates within W=2.5e-2 of the computed min.
// Single 64KB LDS A-table -> 66KB LDS -> 2 blocks/CU.
// Measured r11: 44.1us total, absmax 9.77e-4.

#define C_DIM 64
#define K_EMB 512
#define NVEC (32 * 64 * 64)     // 131072
#define BLK 256                 // 4 waves
#define VPW 64                  // vectors per wave
#define NPB 256                 // vectors per block
#define GRID (NVEC / NPB)       // 512 = 2 blocks/CU
#define KT (K_EMB / 16)         // 32 k-tiles
#define NT 4                    // 16-vector groups per wave
#define WINF 2.5e-2f

typedef __attribute__((ext_vector_type(8))) _Float16 f16x8;
typedef __attribute__((ext_vector_type(4))) float f32x4;

// ws layout (bytes)
#define WS_E2   0
#define WS_AE   4096
#define WS_PART (4096 + 65536)

__device__ inline bool lessidx(float s, int i, float t, int j) {
    return (s < t) || (s == t && i < j);
}

__device__ __forceinline__ double dist64(const float4* __restrict__ xq,
                                         const float* __restrict__ ep) {
    const float4* e4 = (const float4*)ep;
    double s = 0.0;
#pragma unroll
    for (int i = 0; i < 16; ++i) {
        float4 xv = xq[i]; float4 a = e4[i];
        double d;
        d = (double)xv.x - (double)a.x; s = fma(d, d, s);
        d = (double)xv.y - (double)a.y; s = fma(d, d, s);
        d = (double)xv.z - (double)a.z; s = fma(d, d, s);
        d = (double)xv.w - (double)a.w; s = fma(d, d, s);
    }
    return s;
}

// ---- prep: e2[k]; frag-linear f16 table of (-2*emb) ----
// frag layout: region r = kt*2 + s, lane l holds 8 f16 =
// A[row = kt*16 + (l&15)][c = 32*s + (l>>4)*8 + j], at (r*64+l)*8 halfs.
__global__ __launch_bounds__(512) void vq_prep(const float* __restrict__ emb,
                                               float* __restrict__ e2,
                                               short* __restrict__ ae) {
    const int t = blockIdx.x * 512 + threadIdx.x;   // 0..4095
    const int l = t & 63;
    const int kt2 = t >> 6;
    const int row = (kt2 >> 1) * 16 + (l & 15);
    const int cb  = (kt2 & 1) * 32 + (l >> 4) * 8;
    const float* src = emb + row * C_DIM + cb;
    f16x8 vh;
#pragma unroll
    for (int j = 0; j < 8; ++j) vh[j] = (_Float16)(-2.0f * src[j]);
    *(f16x8*)(ae + (size_t)t * 8) = vh;

    if (t < K_EMB) {
        const float* r = emb + t * C_DIM;
        float s = 0.f;
#pragma unroll
        for (int c = 0; c < C_DIM; ++c) s += r[c] * r[c];
        e2[t] = s;
    }
}

__global__ __launch_bounds__(BLK, 2) void vq_main(
    const float* __restrict__ x,
    const float* __restrict__ emb,
    const float* __restrict__ e2g,
    const short* __restrict__ ae_g,
    float* __restrict__ out,
    double* __restrict__ partials)
{
    __shared__ __align__(16) short s_ae[K_EMB * C_DIM];  // 64 KB
    __shared__ __align__(16) float s_e2[K_EMB];          // 2 KB
    __shared__ double s_wsum[BLK / 64];

    const int tid  = threadIdx.x;
    const int lane = tid & 63;
    const int wid  = tid >> 6;
    const int lr   = lane & 15;
    const int lh   = lane >> 4;
    const int nbase = blockIdx.x * NPB + wid * VPW;

    // ---- x loads first (fly during staging) ----
    float4 xr[NT * 4];
#pragma unroll
    for (int nt = 0; nt < NT; ++nt) {
        const float* xp = x + (size_t)(nbase + nt * 16 + lr) * C_DIM;
#pragma unroll
        for (int s = 0; s < 2; ++s) {
            xr[nt * 4 + s * 2 + 0] = *(const float4*)(xp + s * 32 + lh * 8);
            xr[nt * 4 + s * 2 + 1] = *(const float4*)(xp + s * 32 + lh * 8 + 4);
        }
    }

    // ---- stage table (64KB) + e2 into LDS ----
    {
        const float4* srca = (const float4*)ae_g;
        float4* dsta = (float4*)s_ae;
#pragma unroll
        for (int i = 0; i < 16; ++i) dsta[tid + i * BLK] = srca[tid + i * BLK];
        s_e2[tid] = e2g[tid];
        s_e2[tid + 256] = e2g[tid + 256];
    }
    __syncthreads();

    // ---- x -> f16 hi/lo B-fragments, x2 partials ----
    f16x8 xh[NT][2], xl[NT][2];
    float x2p[NT];
#pragma unroll
    for (int nt = 0; nt < NT; ++nt) {
        x2p[nt] = 0.f;
#pragma unroll
        for (int s = 0; s < 2; ++s) {
            float4 a = xr[nt * 4 + s * 2 + 0];
            float4 b = xr[nt * 4 + s * 2 + 1];
            float vv[8] = {a.x, a.y, a.z, a.w, b.x, b.y, b.z, b.w};
#pragma unroll
            for (int j = 0; j < 8; ++j) {
                float v = vv[j];
                x2p[nt] += v * v;
                _Float16 h = (_Float16)v;
                xh[nt][s][j] = h;
                xl[nt][s][j] = (_Float16)(v - (float)h);
            }
        }
    }

    // ---- k-loop: 16 MFMA/kt, per-group trunc-packed top-2 ----
    float pb1[NT] = {1e30f, 1e30f, 1e30f, 1e30f};
    float pb2[NT] = {1e30f, 1e30f, 1e30f, 1e30f};
    const f16x8* ab = (const f16x8*)s_ae + lane;

#pragma unroll 2
    for (int kt = 0; kt < KT; ++kt) {
        f16x8 a0 = ab[kt * 128], a1 = ab[kt * 128 + 64];
        f32x4 ev = *(const f32x4*)(s_e2 + kt * 16 + lh * 4);
        f32x4 c[NT];
#pragma unroll
        for (int nt = 0; nt < NT; ++nt) c[nt] = ev;
#pragma unroll
        for (int nt = 0; nt < NT; ++nt)
            c[nt] = __builtin_amdgcn_mfma_f32_16x16x32_f16(a0, xh[nt][0], c[nt], 0, 0, 0);
#pragma unroll
        for (int nt = 0; nt < NT; ++nt)
            c[nt] = __builtin_amdgcn_mfma_f32_16x16x32_f16(a1, xh[nt][1], c[nt], 0, 0, 0);
#pragma unroll
        for (int nt = 0; nt < NT; ++nt)
            c[nt] = __builtin_amdgcn_mfma_f32_16x16x32_f16(a0, xl[nt][0], c[nt], 0, 0, 0);
#pragma unroll
        for (int nt = 0; nt < NT; ++nt)
            c[nt] = __builtin_amdgcn_mfma_f32_16x16x32_f16(a1, xl[nt][1], c[nt], 0, 0, 0);

        const unsigned kb4 = (unsigned)(kt * 4);
#pragma unroll
        for (int nt = 0; nt < NT; ++nt) {
            unsigned q0 = (__float_as_uint(c[nt][0]) & 0xFFFFFF80u) | (kb4 + 0);
            unsigned q1 = (__float_as_uint(c[nt][1]) & 0xFFFFFF80u) | (kb4 + 1);
            unsigned q2 = (__float_as_uint(c[nt][2]) & 0xFFFFFF80u) | (kb4 + 2);
            unsigned q3 = (__float_as_uint(c[nt][3]) & 0xFFFFFF80u) | (kb4 + 3);
            float f0 = __uint_as_float(q0), f1 = __uint_as_float(q1);
            float f2 = __uint_as_float(q2), f3 = __uint_as_float(q3);
            float lo = fminf(f0, f1), hi = fmaxf(f0, f1);
            pb2[nt] = fminf(fminf(pb2[nt], fmaxf(pb1[nt], lo)), hi);
            pb1[nt] = fminf(pb1[nt], lo);
            lo = fminf(f2, f3); hi = fmaxf(f2, f3);
            pb2[nt] = fminf(fminf(pb2[nt], fmaxf(pb1[nt], lo)), hi);
            pb1[nt] = fminf(pb1[nt], lo);
        }
    }

    // ---- per-nt: unpack, merge, conditional 8-candidate fp64 refine ----
    double dsum = 0.0;
#pragma unroll
    for (int nt = 0; nt < NT; ++nt) {
        unsigned u1 = __float_as_uint(pb1[nt]);
        unsigned u2 = __float_as_uint(pb2[nt]);
        int loc1 = u1 & 127, loc2 = u2 & 127;
        float b1 = __uint_as_float(u1 & 0xFFFFFF80u);
        float b2 = __uint_as_float(u2 & 0xFFFFFF80u);
        int i1 = ((loc1 >> 2) << 4) + lh * 4 + (loc1 & 3);
        int i2 = ((loc2 >> 2) << 4) + lh * 4 + (loc2 & 3);
        // keep this lane's own candidates for the refine path
        const float os1 = b1, os2 = b2;
        const int   oi1 = i1, oi2 = i2;

        float xx = x2p[nt];
#pragma unroll
        for (int off = 16; off <= 32; off <<= 1) {
            float ob1 = __shfl_xor(b1, off, 64);
            int   oI1 = __shfl_xor(i1, off, 64);
            float ob2 = __shfl_xor(b2, off, 64);
            int   oI2 = __shfl_xor(i2, off, 64);
            float oxx = __shfl_xor(xx, off, 64);
            xx += oxx;
            bool to = lessidx(ob1, oI1, b1, i1);
            float w1 = to ? ob1 : b1;  int wi1 = to ? oI1 : i1;
            float l1 = to ? b1 : ob1;  int li1 = to ? i1 : oI1;
            float c2 = to ? ob2 : b2;  int ci2 = to ? oI2 : i2;
            bool t2 = lessidx(l1, li1, c2, ci2);
            b1 = w1; i1 = wi1;
            b2 = t2 ? l1 : c2; i2 = t2 ? li1 : ci2;
        }

        const int n = nbase + nt * 16 + lr;
        const float4* xq = (const float4*)(x + (size_t)n * C_DIM);

        int bw;
        double md;
        // condition is uniform across the 4 lanes of a column -> shfl-safe
        if (b2 - b1 < WINF) {
            // exact fp64 over all own candidates within W of global min
            bool f1 = (os1 <= b1 + WINF);
            bool f2 = (os2 <= b1 + WINF);
            double d1 = 1e300, d2 = 1e300;
            if (f1) d1 = dist64(xq, emb + (size_t)oi1 * C_DIM);
            if (f2) d2 = dist64(xq, emb + (size_t)oi2 * C_DIM);
            bool t = (d2 < d1) || (d2 == d1 && oi2 < oi1);
            double dl = t ? d2 : d1;
            int    il = t ? oi2 : oi1;
#pragma unroll
            for (int off = 16; off <= 32; off <<= 1) {
                double od = __shfl_xor(dl, off, 64);
                int    oi = __shfl_xor(il, off, 64);
                bool tk = (od < dl) || (od == dl && oi < il);
                dl = tk ? od : dl;
                il = tk ? oi : il;
            }
            bw = il;
            md = dl;
        } else {
            bw = i1;
            md = (double)xx + (double)b1;
        }

        if (lane < 16) dsum += md;

        // per-wave gather: 16 vectors x 16 float4 chunks, 4 iters of 64 lanes
        {
            const int v  = lane >> 2;
            const int c0 = lane & 3;
            const int w  = __shfl(bw, v);
            const size_t rowb = ((size_t)(nbase + nt * 16 + v)) * 16;
            const float4* ep = (const float4*)emb + (size_t)w * 16;
            float4* op = (float4*)out;
#pragma unroll
            for (int it = 0; it < 4; ++it) op[rowb + c0 + it * 4] = ep[c0 + it * 4];
        }
    }

    // ---- loss partial ----
#pragma unroll
    for (int off = 1; off <= 8; off <<= 1) dsum += __shfl_xor(dsum, off, 64);
    if (lane == 0) s_wsum[wid] = dsum;
    __syncthreads();
    if (tid == 0) {
        double t = 0.0;
#pragma unroll
        for (int i = 0; i < BLK / 64; ++i) t += s_wsum[i];
        partials[blockIdx.x] = t;
    }
}

__global__ __launch_bounds__(512) void vq_finalize(const double* __restrict__ partials,
                                                   float* __restrict__ out) {
    double v = partials[threadIdx.x];   // 512 partials
#pragma unroll
    for (int off = 32; off; off >>= 1) v += __shfl_down(v, off, 64);
    __shared__ double ls[8];
    const int lane = threadIdx.x & 63;
    const int wid  = threadIdx.x >> 6;
    if (lane == 0) ls[wid] = v;
    __syncthreads();
    if (threadIdx.x == 0) {
        double t = 0.0;
#pragma unroll
        for (int i = 0; i < 8; ++i) t += ls[i];
        double mean = t / (double)((size_t)NVEC * C_DIM);
        out[(size_t)NVEC * C_DIM] = (float)(1.25 * mean);
    }
}

extern "C" void kernel_launch(void* const* d_in, const int* in_sizes, int n_in,
                              void* d_out, int out_size, void* d_ws, size_t ws_size,
                              hipStream_t stream) {
    const float* x   = (const float*)d_in[0];
    const float* emb = (const float*)d_in[1];
    float* out = (float*)d_out;

    float*  e2       = (float*)((char*)d_ws + WS_E2);
    short*  ae       = (short*)((char*)d_ws + WS_AE);
    double* partials = (double*)((char*)d_ws + WS_PART);

    vq_prep<<<8, 512, 0, stream>>>(emb, e2, ae);
    vq_main<<<GRID, BLK, 0, stream>>>(x, emb, e2, ae, out, partials);
    vq_finalize<<<1, 512, 0, stream>>>(partials, out);
}